// Round 11
// baseline (242.444 us; speedup 1.0000x reference)
//
#include <hip/hip_runtime.h>
#include <hip/hip_bf16.h>

// B=1 T=64 W=88 HP=48 F0=53 HL=12 GATES=48 NU=24 NH=4 HD=6 K=25
#define NPIX (64*88)          // 5632
#define NSEQ 88
#define TT 64
#define F0 53
#define GATES 48
#define LOG2E 1.4426950408889634f

typedef __hip_bfloat16 bf16;

__device__ __forceinline__ float frcp(float x){ return __builtin_amdgcn_rcpf(x); }
__device__ __forceinline__ float fexp2(float x){ return __builtin_amdgcn_exp2f(x); }
__device__ __forceinline__ float blo(unsigned u){ return __uint_as_float(u<<16); }
__device__ __forceinline__ float bhi(unsigned u){ return __uint_as_float(u & 0xffff0000u); }

// readlane broadcast (constant lane after inlining)
__device__ __forceinline__ float rl(float v, int l){
  return __int_as_float(__builtin_amdgcn_readlane(__float_as_int(v), l));
}
// DPP quad broadcast of lane K within each quad
template<int K> __device__ __forceinline__ float qbcast(float v){
  constexpr int ctrl = K | (K<<2) | (K<<4) | (K<<6);
  return __int_as_float(__builtin_amdgcn_update_dpp(0, __float_as_int(v), ctrl, 0xf, 0xf, true));
}

// ---- wave64 reductions on the VALU pipe (DPP), no LDS-pipe traffic ----
template<int CTRL> __device__ __forceinline__ float dpp_add(float v){
  return v + __int_as_float(__builtin_amdgcn_update_dpp(0, __float_as_int(v), CTRL, 0xf, 0xf, true));
}
template<int CTRL> __device__ __forceinline__ float dpp_max(float v){
  int vi = __float_as_int(v);
  return fmaxf(v, __int_as_float(__builtin_amdgcn_update_dpp(vi, vi, CTRL, 0xf, 0xf, false)));
}
__device__ __forceinline__ float wred_sum(float v){
  v = dpp_add<0x111>(v); v = dpp_add<0x112>(v); v = dpp_add<0x114>(v); v = dpp_add<0x118>(v);
  v = dpp_add<0x142>(v); v = dpp_add<0x143>(v);   // row_bcast:15, row_bcast:31
  return rl(v,63);
}
__device__ __forceinline__ float wred_max(float v){
  v = dpp_max<0x111>(v); v = dpp_max<0x112>(v); v = dpp_max<0x114>(v); v = dpp_max<0x118>(v);
  v = dpp_max<0x142>(v); v = dpp_max<0x143>(v);
  return rl(v,63);
}

// One LSTM direction. Quad-interleaved lane map: lane = 4*u + grp,
// grp 0:i 1:f 2:g 3:o, unit u=lane>>2 (lanes 48-63 duplicate unit 11).
// gbuf entries and whh PRE-SCALED by log2e -> activations use native exp2.
__device__ __forceinline__ void lstm_dir(const float* __restrict__ whh,
    const float* gb_base, float* ybuf, int d, int lane){
  int u = lane >> 2, grp = lane & 3;
  int uc = (u < 12) ? u : 11;
  int j = grp*12 + uc;
  float w[12];
  const float* wb = whh + (d*GATES + j)*12;
  #pragma unroll
  for (int m=0;m<12;++m) w[m] = wb[m]*LOG2E;
  float negs = (grp==2) ? -2.f : -1.f;      // tanh(x)=2*sigm(2x)-1
  float amul = (grp==2) ?  2.f :  1.f;
  float aadd = (grp==2) ? -1.f :  0.f;
  const float* gb = gb_base + (d*TT)*49 + j;
  float hval = 0.f, cval = 0.f;
  int t0 = d ? (TT-1) : 0;
  float gnext = gb[t0*49];
  bool wr = (grp==0) && (u < 12);
  for (int s=0;s<TT;++s){
    int t = d ? (TT-1-s) : s;
    float gg = gnext;
    int tn = d ? max(TT-2-s,0) : min(s+1,TT-1);
    gnext = gb[tn*49];
    float h0=rl(hval,0),  h1=rl(hval,4),  h2=rl(hval,8),   h3=rl(hval,12);
    float h4=rl(hval,16), h5=rl(hval,20), h6=rl(hval,24),  h7=rl(hval,28);
    float h8=rl(hval,32), h9=rl(hval,36), h10=rl(hval,40), h11=rl(hval,44);
    float a0 = gg + h0*w[0] + h4*w[4] + h8*w[8];
    float a1 = h1*w[1] + h5*w[5] + h9*w[9];
    float a2 = h2*w[2] + h6*w[6] + h10*w[10];
    float a3 = h3*w[3] + h7*w[7] + h11*w[11];
    float dot = (a0+a1)+(a2+a3);               // log2e-scaled
    float act = amul*frcp(1.f + fexp2(negs*dot)) + aadd;
    float ai = qbcast<0>(act);
    float af = qbcast<1>(act);
    float ag = qbcast<2>(act);
    float ao = qbcast<3>(act);
    float cn = af*cval + ai*ag;
    float th = 2.f*frcp(1.f + fexp2(-2.885390081777927f*cn)) - 1.f;
    hval = ao*th; cval = cn;
    if (wr) ybuf[t*25 + d*12 + u] = hval;
  }
}

// ============ D1: whole LSTM stack + qkv. 88 blocks x 1024 threads =========
__global__ __launch_bounds__(1024, 4) void k_core(
    const float* __restrict__ feat, const int* __restrict__ cond,
    const float* __restrict__ mask, const float* __restrict__ emb,
    const float* __restrict__ wih0, const float* __restrict__ whh0,
    const float* __restrict__ bih0, const float* __restrict__ bhh0,
    const float* __restrict__ wih1, const float* __restrict__ whh1,
    const float* __restrict__ bih1, const float* __restrict__ bhh1,
    const float* __restrict__ qkv_w, const float* __restrict__ qkv_b,
    float* __restrict__ q, bf16* __restrict__ kh, bf16* __restrict__ vh){
  int n = (blockIdx.x & 7)*11 + (blockIdx.x >> 3);   // XCD-aware remap
  int tid = threadIdx.x;
  int wave = tid >> 6; int lane = tid & 63;
  __shared__ float smem[12864];
  float* gbuf = smem;                 // 2*64*49 = 6272
  float* sx   = smem + 6272;          // 64*53  = 3392
  float* y0   = smem + 6272+3392;     // 64*25  = 1600
  float* y1   = smem + 6272+4992;     // 64*25  = 1600
  float* outb = smem;                 // 64*73  = 4672 (aliases gbuf, used last)

  for (int idx = tid; idx < TT*F0; idx += 1024){
    int t = idx / F0, f = idx - t*F0;
    float v;
    if (f < 48)      v = feat[(t*48 + f)*88 + n];
    else if (f < 52) v = emb[cond[t*88+n]*4 + (f-48)];
    else             v = mask[t*88+n];
    sx[idx] = v;
  }
  __syncthreads();

  // ---- phase A: layer-0 gate GEMM (lane = t, wave = 6 gate rows) ----
  {
    int wu = __builtin_amdgcn_readfirstlane(wave);
    int dd = wu >> 3, jg = wu & 7;
    const float* w0 = wih0 + (dd*GATES + jg*6)*F0;
    const float* xr = sx + lane*F0;
    float a0[6], a1[6];
    #pragma unroll
    for (int k=0;k<6;++k){
      int j = dd*GATES + jg*6 + k;
      a0[k] = bih0[j] + bhh0[j];
      a1[k] = 0.f;
    }
    #pragma unroll
    for (int f=0; f<52; f+=2){
      float x0 = xr[f], x1 = xr[f+1];
      #pragma unroll
      for (int k=0;k<6;++k){
        a0[k] += x0*w0[k*F0+f];
        a1[k] += x1*w0[k*F0+f+1];
      }
    }
    {
      float x0 = xr[52];
      #pragma unroll
      for (int k=0;k<6;++k) a0[k] += x0*w0[k*F0+52];
    }
    float* go = gbuf + (dd*TT + lane)*49 + jg*6;
    #pragma unroll
    for (int k=0;k<6;++k) go[k] = (a0[k] + a1[k])*LOG2E;
  }
  __syncthreads();

  if (wave < 2) lstm_dir(whh0, gbuf, y0, wave, lane);
  __syncthreads();

  // ---- phase B: layer-1 gate GEMM ----
  {
    int wu = __builtin_amdgcn_readfirstlane(wave);
    int dd = wu >> 3, jg = wu & 7;
    const float* w1p = wih1 + (dd*GATES + jg*6)*24;
    const float* xr = y0 + lane*25;
    float a0[6], a1[6];
    #pragma unroll
    for (int k=0;k<6;++k){
      int j = dd*GATES + jg*6 + k;
      a0[k] = bih1[j] + bhh1[j];
      a1[k] = 0.f;
    }
    #pragma unroll
    for (int c=0; c<24; c+=2){
      float x0 = xr[c], x1 = xr[c+1];
      #pragma unroll
      for (int k=0;k<6;++k){
        a0[k] += x0*w1p[k*24+c];
        a1[k] += x1*w1p[k*24+c+1];
      }
    }
    float* go = gbuf + (dd*TT + lane)*49 + jg*6;
    #pragma unroll
    for (int k=0;k<6;++k) go[k] = (a0[k] + a1[k])*LOG2E;
  }
  __syncthreads();

  if (wave < 2) lstm_dir(whh1, gbuf, y1, wave, lane);
  __syncthreads();

  // ---- qkv GEMM (72 x 24), waves 0-11, lane = t ----
  if (wave < 12){
    int wu = __builtin_amdgcn_readfirstlane(wave);
    int g0 = wu*6;
    const float* qw = qkv_w + g0*24;
    const float* xr = y1 + lane*25;
    float a0[6], a1[6];
    #pragma unroll
    for (int k=0;k<6;++k){ a0[k] = qkv_b[g0+k]; a1[k] = 0.f; }
    #pragma unroll
    for (int c=0; c<24; c+=2){
      float x0 = xr[c], x1 = xr[c+1];
      #pragma unroll
      for (int k=0;k<6;++k){
        a0[k] += x0*qw[k*24+c];
        a1[k] += x1*qw[k*24+c+1];
      }
    }
    float* oo = outb + lane*73 + g0;
    #pragma unroll
    for (int k=0;k<6;++k) oo[k] = a0[k] + a1[k];
  }
  __syncthreads();

  for (int idx = tid; idx < TT*72; idx += 1024){
    int gq = idx % 72; int t = idx / 72;
    int p = t*88 + n;
    float acc = outb[t*73 + gq];
    int s = gq/24, rem = gq - s*24;
    if (s==0) q[p*24+rem] = acc*0.4082482904638631f;   // 1/sqrt(HD)
    else {
      int hh = rem/6, pos = rem - hh*6;
      bf16* dst = (s==1) ? kh : vh;
      dst[((size_t)hh*NPIX + p)*8 + pos] = __float2bfloat16(acc);
    }
  }
}

// ============ D2/D4: natten, 2x4 tile x 1 head, wave = pixel ===============
// 2816 blocks x 512 thr (8 waves). K,V staged to LDS PRE-UNPACKED to f32
// (26x28 = 728 slots x 6 floats; stride-6 -> 2-way bank alias, free).
// Division-free incremental (a,cc) window walk (+2,+14 with carry per 64).
// Inner math identical fp32 sequence to R10 -> bit-identical output.
__global__ __launch_bounds__(512, 8) void k_nat(
    const float* __restrict__ q, const bf16* __restrict__ kh,
    const bf16* __restrict__ vh, const float* __restrict__ rpb,
    float* __restrict__ ao){
  int bid = blockIdx.x;
  int b = (bid & 7)*352 + (bid >> 3);          // XCD-aware remap (2816 = 8*352)
  int h = b / 704; int t = b - h*704;          // h-major: tile L2 locality
  int ti = t / 22, tj = t - ti*22;
  int i0 = ti*2, j0 = tj*4;
  int tid = threadIdx.x;
  int w = tid >> 6; int lane = tid & 63;
  int osi = min(max(i0-12,0), 38);             // 26 staged rows
  int osj = min(max(j0-12,0), 60);             // 28 staged cols

  __shared__ float kt[728*6];                  // 17472 B
  __shared__ float vt[728*6];                  // 17472 B (total 34.9 KB)

  const uint4* kg = (const uint4*)kh;
  const uint4* vg = (const uint4*)vh;
  for (int idx = tid; idx < 728; idx += 512){
    int a = idx / 28, cc = idx - a*28;
    int src = h*NPIX + (osi + a)*88 + (osj + cc);   // no clamps needed
    uint4 kk = kg[src];
    uint4 vv = vg[src];
    float* kd = kt + idx*6;
    kd[0]=blo(kk.x); kd[1]=bhi(kk.x); kd[2]=blo(kk.y);
    kd[3]=bhi(kk.y); kd[4]=blo(kk.z); kd[5]=bhi(kk.z);
    float* vd = vt + idx*6;
    vd[0]=blo(vv.x); vd[1]=bhi(vv.x); vd[2]=blo(vv.y);
    vd[3]=bhi(vv.y); vd[4]=blo(vv.z); vd[5]=bhi(vv.z);
  }
  __syncthreads();

  // ---- per-wave pixel ----
  int pi = i0 + (w >> 2), pj = j0 + (w & 3);
  int p = pi*88 + pj;
  int si = min(max(pi-12,0),39), sj = min(max(pj-12,0),63);
  int kbase = (si - osi)*28 + (sj - osj);
  int rbi = si - pi + 24, rbj = sj - pj + 24;
  const float* rpbh = rpb + (h*49 + rbi)*49 + rbj;

  float qv[6];
  #pragma unroll
  for (int d=0; d<6; ++d) qv[d] = q[p*24 + h*6 + d];

  float lgv[10];
  float lmax = -1e30f;
  int a0w = lane/25, c0w = lane - (lane/25)*25;     // one-time division
  {
    int a = a0w, cc = c0w;
    #pragma unroll
    for (int it=0; it<10; ++it){
      bool ok = (it < 9) || (lane < 49);
      int slot = ok ? (kbase + a*28 + cc) : 0;
      int ro   = ok ? (a*49 + cc) : 0;
      const float* kd = kt + slot*6;
      float lg = qv[0]*kd[0]+qv[1]*kd[1]+qv[2]*kd[2]
               + qv[3]*kd[3]+qv[4]*kd[4]+qv[5]*kd[5];
      lg += rpbh[ro];
      lg = ok ? lg : -1e30f;
      lgv[it] = lg;
      lmax = fmaxf(lmax, lg);
      cc += 14; bool cy = cc >= 25;
      cc = cy ? cc - 25 : cc;
      a += cy ? 3 : 2;
    }
  }
  lmax = wred_max(lmax);
  float lsum = 0.f;
  #pragma unroll
  for (int it=0; it<10; ++it){
    float pe = __expf(lgv[it]-lmax);
    lgv[it] = pe; lsum += pe;
  }
  lsum = wred_sum(lsum);
  float acc[6] = {0,0,0,0,0,0};
  {
    int a = a0w, cc = c0w;
    #pragma unroll
    for (int it=0; it<10; ++it){
      bool ok = (it < 9) || (lane < 49);
      int slot = ok ? (kbase + a*28 + cc) : 0;
      const float* vd = vt + slot*6;
      float pe = lgv[it];                       // 0 for invalid lanes
      acc[0] += pe*vd[0]; acc[1] += pe*vd[1];
      acc[2] += pe*vd[2]; acc[3] += pe*vd[3];
      acc[4] += pe*vd[4]; acc[5] += pe*vd[5];
      cc += 14; bool cy = cc >= 25;
      cc = cy ? cc - 25 : cc;
      a += cy ? 3 : 2;
    }
  }
  float inv = frcp(lsum);
  #pragma unroll
  for (int d=0; d<6; ++d) acc[d] = wred_sum(acc[d])*inv;

  if (lane == 0){
    float* aop = ao + p*24 + h*6;
    #pragma unroll
    for (int d=0; d<6; ++d) aop[d] = acc[d];
  }
}

// ============ D3: epilogue layer 1: proj + qkv -> q2/kh2/vh2 ===============
__global__ __launch_bounds__(1024) void k_ep0(const float* __restrict__ ao,
    const float* __restrict__ pw, const float* __restrict__ pb,
    const float* __restrict__ qkv_w, const float* __restrict__ qkv_b,
    float* __restrict__ q2, bf16* __restrict__ kh2, bf16* __restrict__ vh2){
  int p0 = blockIdx.x*64; int tid = threadIdx.x;
  __shared__ float ar[64*25];
  __shared__ float xr[64*25];
  for (int idx = tid; idx < 64*24; idx += 1024){
    int px = idx / 24, c = idx - px*24;
    ar[px*25 + c] = ao[p0*24 + idx];
  }
  __syncthreads();
  for (int idx = tid; idx < 64*24; idx += 1024){
    int px = idx / 24, c = idx - px*24;
    float acc = pb[c];
    const float* wr = pw + c*24;
    const float* arow = ar + px*25;
    #pragma unroll
    for (int k=0;k<24;++k) acc += arow[k]*wr[k];
    xr[px*25 + c] = acc;
  }
  __syncthreads();
  for (int idx = tid; idx < 64*72; idx += 1024){
    int px = idx / 72, g = idx - px*72;
    float acc = qkv_b[g];
    const float* wr = qkv_w + g*24;
    const float* xrow = xr + px*25;
    #pragma unroll
    for (int k=0;k<24;++k) acc += xrow[k]*wr[k];
    int p = p0 + px;
    int sg = g/24, rem = g - sg*24;
    if (sg==0) q2[p*24+rem] = acc*0.4082482904638631f;
    else {
      int hh = rem/6, pos = rem - hh*6;
      bf16* dst = (sg==1) ? kh2 : vh2;
      dst[((size_t)hh*NPIX + p)*8 + pos] = __float2bfloat16(acc);
    }
  }
}

// ============ D5: epilogue layer 2: proj + final head -> out ===============
__global__ __launch_bounds__(1024) void k_ep1(const float* __restrict__ ao,
    const float* __restrict__ pw, const float* __restrict__ pb,
    const float* __restrict__ ow, const float* __restrict__ ob,
    float* __restrict__ out){
  int p0 = blockIdx.x*64; int tid = threadIdx.x;
  __shared__ float ar[64*25];
  __shared__ float xr[64*25];
  for (int idx = tid; idx < 64*24; idx += 1024){
    int px = idx / 24, c = idx - px*24;
    ar[px*25 + c] = ao[p0*24 + idx];
  }
  __syncthreads();
  for (int idx = tid; idx < 64*24; idx += 1024){
    int px = idx / 24, c = idx - px*24;
    float acc = pb[c];
    const float* wr = pw + c*24;
    const float* arow = ar + px*25;
    #pragma unroll
    for (int k=0;k<24;++k) acc += arow[k]*wr[k];
    xr[px*25 + c] = acc;
  }
  __syncthreads();
  if (tid < 64*5){
    int px = tid / 5, c = tid - px*5;
    float acc = ob[c];
    const float* wr = ow + c*24;
    const float* xrow = xr + px*25;
    #pragma unroll
    for (int k=0;k<24;++k) acc += xrow[k]*wr[k];
    out[(p0 + px)*5 + c] = acc;
  }
}

extern "C" void kernel_launch(void* const* d_in, const int* in_sizes, int n_in,
                              void* d_out, int out_size, void* d_ws, size_t ws_size,
                              hipStream_t stream) {
  const float* feat    = (const float*)d_in[0];
  const int*   cond    = (const int*)  d_in[1];
  const float* mask    = (const float*)d_in[2];
  const float* emb     = (const float*)d_in[3];
  const float* w_ih_l0 = (const float*)d_in[4];
  const float* w_hh_l0 = (const float*)d_in[5];
  const float* b_ih_l0 = (const float*)d_in[6];
  const float* b_hh_l0 = (const float*)d_in[7];
  const float* w_ih_l1 = (const float*)d_in[8];
  const float* w_hh_l1 = (const float*)d_in[9];
  const float* b_ih_l1 = (const float*)d_in[10];
  const float* b_hh_l1 = (const float*)d_in[11];
  const float* qkv_w   = (const float*)d_in[12];
  const float* qkv_b   = (const float*)d_in[13];
  const float* rpb     = (const float*)d_in[14];
  const float* proj_w  = (const float*)d_in[15];
  const float* proj_b  = (const float*)d_in[16];
  const float* out_w   = (const float*)d_in[17];
  const float* out_b   = (const float*)d_in[18];
  float* out = (float*)d_out;

  float* ws  = (float*)d_ws;
  float* Q1  = ws;                    // 135168 floats
  float* Q2  = Q1 + 135168;           // 135168
  float* AO  = Q2 + 135168;           // 135168
  bf16*  KH1 = (bf16*)(AO + 135168);  // 180224 halves each
  bf16*  VH1 = KH1 + 180224;
  bf16*  KH2 = VH1 + 180224;
  bf16*  VH2 = KH2 + 180224;

  k_core<<<NSEQ, 1024, 0, stream>>>(
      feat, cond, mask, emb,
      w_ih_l0, w_hh_l0, b_ih_l0, b_hh_l0,
      w_ih_l1, w_hh_l1, b_ih_l1, b_hh_l1,
      qkv_w, qkv_b, Q1, KH1, VH1);

  k_nat<<<8*352, 512, 0, stream>>>(Q1, KH1, VH1, rpb, AO);

  k_ep0<<<NPIX/64, 1024, 0, stream>>>(AO, proj_w, proj_b, qkv_w, qkv_b,
      Q2, KH2, VH2);

  k_nat<<<8*352, 512, 0, stream>>>(Q2, KH2, VH2, rpb, AO);

  k_ep1<<<NPIX/64, 1024, 0, stream>>>(AO, proj_w, proj_b, out_w, out_b, out);
}

// Round 12
// 175.860 us; speedup vs baseline: 1.3786x; 1.3786x over previous
//
#include <hip/hip_runtime.h>
#include <hip/hip_bf16.h>

// B=1 T=64 W=88 HP=48 F0=53 HL=12 GATES=48 NU=24 NH=4 HD=6 K=25
#define NPIX (64*88)          // 5632
#define NSEQ 88
#define TT 64
#define F0 53
#define GATES 48
#define LOG2E 1.4426950408889634f

typedef __hip_bfloat16 bf16;

__device__ __forceinline__ float frcp(float x){ return __builtin_amdgcn_rcpf(x); }
__device__ __forceinline__ float fexp2(float x){ return __builtin_amdgcn_exp2f(x); }
__device__ __forceinline__ float blo(unsigned u){ return __uint_as_float(u<<16); }
__device__ __forceinline__ float bhi(unsigned u){ return __uint_as_float(u & 0xffff0000u); }

// readlane broadcast (constant lane after inlining)
__device__ __forceinline__ float rl(float v, int l){
  return __int_as_float(__builtin_amdgcn_readlane(__float_as_int(v), l));
}
// DPP quad broadcast of lane K within each quad
template<int K> __device__ __forceinline__ float qbcast(float v){
  constexpr int ctrl = K | (K<<2) | (K<<4) | (K<<6);
  return __int_as_float(__builtin_amdgcn_update_dpp(0, __float_as_int(v), ctrl, 0xf, 0xf, true));
}

// ---- wave64 reductions on the VALU pipe (DPP), no LDS-pipe traffic ----
template<int CTRL> __device__ __forceinline__ float dpp_add(float v){
  return v + __int_as_float(__builtin_amdgcn_update_dpp(0, __float_as_int(v), CTRL, 0xf, 0xf, true));
}
template<int CTRL> __device__ __forceinline__ float dpp_max(float v){
  int vi = __float_as_int(v);
  return fmaxf(v, __int_as_float(__builtin_amdgcn_update_dpp(vi, vi, CTRL, 0xf, 0xf, false)));
}
__device__ __forceinline__ float wred_sum(float v){
  v = dpp_add<0x111>(v); v = dpp_add<0x112>(v); v = dpp_add<0x114>(v); v = dpp_add<0x118>(v);
  v = dpp_add<0x142>(v); v = dpp_add<0x143>(v);   // row_bcast:15, row_bcast:31
  return rl(v,63);
}
__device__ __forceinline__ float wred_max(float v){
  v = dpp_max<0x111>(v); v = dpp_max<0x112>(v); v = dpp_max<0x114>(v); v = dpp_max<0x118>(v);
  v = dpp_max<0x142>(v); v = dpp_max<0x143>(v);
  return rl(v,63);
}

// One LSTM direction. Quad-interleaved lane map: lane = 4*u + grp,
// grp 0:i 1:f 2:g 3:o, unit u=lane>>2 (lanes 48-63 duplicate unit 11).
// gbuf entries and whh PRE-SCALED by log2e -> activations use native exp2.
__device__ __forceinline__ void lstm_dir(const float* __restrict__ whh,
    const float* gb_base, float* ybuf, int d, int lane){
  int u = lane >> 2, grp = lane & 3;
  int uc = (u < 12) ? u : 11;
  int j = grp*12 + uc;
  float w[12];
  const float* wb = whh + (d*GATES + j)*12;
  #pragma unroll
  for (int m=0;m<12;++m) w[m] = wb[m]*LOG2E;
  float negs = (grp==2) ? -2.f : -1.f;      // tanh(x)=2*sigm(2x)-1
  float amul = (grp==2) ?  2.f :  1.f;
  float aadd = (grp==2) ? -1.f :  0.f;
  const float* gb = gb_base + (d*TT)*49 + j;
  float hval = 0.f, cval = 0.f;
  int t0 = d ? (TT-1) : 0;
  float gnext = gb[t0*49];
  bool wr = (grp==0) && (u < 12);
  for (int s=0;s<TT;++s){
    int t = d ? (TT-1-s) : s;
    float gg = gnext;
    int tn = d ? max(TT-2-s,0) : min(s+1,TT-1);
    gnext = gb[tn*49];
    float h0=rl(hval,0),  h1=rl(hval,4),  h2=rl(hval,8),   h3=rl(hval,12);
    float h4=rl(hval,16), h5=rl(hval,20), h6=rl(hval,24),  h7=rl(hval,28);
    float h8=rl(hval,32), h9=rl(hval,36), h10=rl(hval,40), h11=rl(hval,44);
    float a0 = gg + h0*w[0] + h4*w[4] + h8*w[8];
    float a1 = h1*w[1] + h5*w[5] + h9*w[9];
    float a2 = h2*w[2] + h6*w[6] + h10*w[10];
    float a3 = h3*w[3] + h7*w[7] + h11*w[11];
    float dot = (a0+a1)+(a2+a3);               // log2e-scaled
    float act = amul*frcp(1.f + fexp2(negs*dot)) + aadd;
    float ai = qbcast<0>(act);
    float af = qbcast<1>(act);
    float ag = qbcast<2>(act);
    float ao = qbcast<3>(act);
    float cn = af*cval + ai*ag;
    float th = 2.f*frcp(1.f + fexp2(-2.885390081777927f*cn)) - 1.f;
    hval = ao*th; cval = cn;
    if (wr) ybuf[t*25 + d*12 + u] = hval;
  }
}

// ============ D1: whole LSTM stack + qkv. 88 blocks x 1024 threads =========
__global__ __launch_bounds__(1024, 4) void k_core(
    const float* __restrict__ feat, const int* __restrict__ cond,
    const float* __restrict__ mask, const float* __restrict__ emb,
    const float* __restrict__ wih0, const float* __restrict__ whh0,
    const float* __restrict__ bih0, const float* __restrict__ bhh0,
    const float* __restrict__ wih1, const float* __restrict__ whh1,
    const float* __restrict__ bih1, const float* __restrict__ bhh1,
    const float* __restrict__ qkv_w, const float* __restrict__ qkv_b,
    float* __restrict__ q, bf16* __restrict__ kh, bf16* __restrict__ vh){
  int n = (blockIdx.x & 7)*11 + (blockIdx.x >> 3);   // XCD-aware remap
  int tid = threadIdx.x;
  int wave = tid >> 6; int lane = tid & 63;
  __shared__ float smem[12864];
  float* gbuf = smem;                 // 2*64*49 = 6272
  float* sx   = smem + 6272;          // 64*53  = 3392
  float* y0   = smem + 6272+3392;     // 64*25  = 1600
  float* y1   = smem + 6272+4992;     // 64*25  = 1600
  float* outb = smem;                 // 64*73  = 4672 (aliases gbuf, used last)

  for (int idx = tid; idx < TT*F0; idx += 1024){
    int t = idx / F0, f = idx - t*F0;
    float v;
    if (f < 48)      v = feat[(t*48 + f)*88 + n];
    else if (f < 52) v = emb[cond[t*88+n]*4 + (f-48)];
    else             v = mask[t*88+n];
    sx[idx] = v;
  }
  __syncthreads();

  // ---- phase A: layer-0 gate GEMM (lane = t, wave = 6 gate rows) ----
  {
    int wu = __builtin_amdgcn_readfirstlane(wave);
    int dd = wu >> 3, jg = wu & 7;
    const float* w0 = wih0 + (dd*GATES + jg*6)*F0;
    const float* xr = sx + lane*F0;
    float a0[6], a1[6];
    #pragma unroll
    for (int k=0;k<6;++k){
      int j = dd*GATES + jg*6 + k;
      a0[k] = bih0[j] + bhh0[j];
      a1[k] = 0.f;
    }
    #pragma unroll
    for (int f=0; f<52; f+=2){
      float x0 = xr[f], x1 = xr[f+1];
      #pragma unroll
      for (int k=0;k<6;++k){
        a0[k] += x0*w0[k*F0+f];
        a1[k] += x1*w0[k*F0+f+1];
      }
    }
    {
      float x0 = xr[52];
      #pragma unroll
      for (int k=0;k<6;++k) a0[k] += x0*w0[k*F0+52];
    }
    float* go = gbuf + (dd*TT + lane)*49 + jg*6;
    #pragma unroll
    for (int k=0;k<6;++k) go[k] = (a0[k] + a1[k])*LOG2E;
  }
  __syncthreads();

  if (wave < 2) lstm_dir(whh0, gbuf, y0, wave, lane);
  __syncthreads();

  // ---- phase B: layer-1 gate GEMM ----
  {
    int wu = __builtin_amdgcn_readfirstlane(wave);
    int dd = wu >> 3, jg = wu & 7;
    const float* w1p = wih1 + (dd*GATES + jg*6)*24;
    const float* xr = y0 + lane*25;
    float a0[6], a1[6];
    #pragma unroll
    for (int k=0;k<6;++k){
      int j = dd*GATES + jg*6 + k;
      a0[k] = bih1[j] + bhh1[j];
      a1[k] = 0.f;
    }
    #pragma unroll
    for (int c=0; c<24; c+=2){
      float x0 = xr[c], x1 = xr[c+1];
      #pragma unroll
      for (int k=0;k<6;++k){
        a0[k] += x0*w1p[k*24+c];
        a1[k] += x1*w1p[k*24+c+1];
      }
    }
    float* go = gbuf + (dd*TT + lane)*49 + jg*6;
    #pragma unroll
    for (int k=0;k<6;++k) go[k] = (a0[k] + a1[k])*LOG2E;
  }
  __syncthreads();

  if (wave < 2) lstm_dir(whh1, gbuf, y1, wave, lane);
  __syncthreads();

  // ---- qkv GEMM (72 x 24), waves 0-11, lane = t ----
  if (wave < 12){
    int wu = __builtin_amdgcn_readfirstlane(wave);
    int g0 = wu*6;
    const float* qw = qkv_w + g0*24;
    const float* xr = y1 + lane*25;
    float a0[6], a1[6];
    #pragma unroll
    for (int k=0;k<6;++k){ a0[k] = qkv_b[g0+k]; a1[k] = 0.f; }
    #pragma unroll
    for (int c=0; c<24; c+=2){
      float x0 = xr[c], x1 = xr[c+1];
      #pragma unroll
      for (int k=0;k<6;++k){
        a0[k] += x0*qw[k*24+c];
        a1[k] += x1*qw[k*24+c+1];
      }
    }
    float* oo = outb + lane*73 + g0;
    #pragma unroll
    for (int k=0;k<6;++k) oo[k] = a0[k] + a1[k];
  }
  __syncthreads();

  for (int idx = tid; idx < TT*72; idx += 1024){
    int gq = idx % 72; int t = idx / 72;
    int p = t*88 + n;
    float acc = outb[t*73 + gq];
    int s = gq/24, rem = gq - s*24;
    if (s==0) q[p*24+rem] = acc*0.4082482904638631f;   // 1/sqrt(HD)
    else {
      int hh = rem/6, pos = rem - hh*6;
      bf16* dst = (s==1) ? kh : vh;
      dst[((size_t)hh*NPIX + p)*8 + pos] = __float2bfloat16(acc);
    }
  }
}

// ============ D2/D3: merged natten layer (tiled, all heads per block) ======
// Block = 2x2 pixel tile x 4 heads = 16 pixel-head waves (1024 threads).
// K+V staged to LDS once for all heads (stride-3 dwords, conflict-free).
// Division-free incremental window walk (validated bit-identical in R11).
// DPP (VALU-pipe) reductions. MODE 0: epilogue proj+qkv -> q2/kh2/vh2.
// MODE 1: epilogue proj+out head -> out.
template<int MODE>
__global__ __launch_bounds__(1024, 8) void k_natten(
    const float* __restrict__ q, const bf16* __restrict__ kh,
    const bf16* __restrict__ vh, const float* __restrict__ rpb,
    const float* __restrict__ pw, const float* __restrict__ pb,
    const float* __restrict__ qkv_w, const float* __restrict__ qkv_b,
    const float* __restrict__ ow, const float* __restrict__ ob,
    float* __restrict__ q2, bf16* __restrict__ kh2, bf16* __restrict__ vh2,
    float* __restrict__ out){
  int bid = blockIdx.x;
  int b = (bid & 7)*176 + (bid >> 3);          // XCD-aware remap (1408 = 8*176)
  int ti = b / 44, tj = b - ti*44;
  int i0 = ti*2, j0 = tj*2;
  int tid = threadIdx.x;
  int w = tid >> 6; int lane = tid & 63;
  int osi = min(max(i0-12,0),39);
  int osj = min(max(j0-12,0),63);

  // staged region: 26 rows x 26 cols x 4 heads; 3 dwords per row (6 bf16)
  __shared__ unsigned kv[16224];               // 64896 B
  unsigned* kt = kv;                           // [4][676*3]
  unsigned* vt = kv + 8112;
  float* aop = (float*)kv;                     // aliases kt after attention
  float* x4  = aop + 96;

  const uint4* kg = (const uint4*)kh;
  const uint4* vg = (const uint4*)vh;
  for (int idx = tid; idx < 2704; idx += 1024){
    int h = idx / 676; int r = idx - h*676;
    int a = r / 26, cc = r - a*26;
    int gi = min(osi + a, 63), gj = min(osj + cc, 87);
    int src = h*NPIX + gi*88 + gj;
    uint4 kr = kg[src];
    uint4 vr = vg[src];
    int o = idx*3;
    kt[o] = kr.x; kt[o+1] = kr.y; kt[o+2] = kr.z;
    vt[o] = vr.x; vt[o+1] = vr.y; vt[o+2] = vr.z;
  }
  __syncthreads();

  int px = w & 3; int h = w >> 2;
  int pi = i0 + (px>>1), pj = j0 + (px&1);
  int p = pi*88 + pj;
  int dsi = min(max(pi-12,0),39) - osi;
  int dsj = min(max(pj-12,0),63) - osj;
  int rbi = osi + dsi - pi + 24;
  int rbj = osj + dsj - pj + 24;
  int hbase = h*2028;                          // h*676*3
  int rowofs = hbase + (dsi*26 + dsj)*3;
  const float* rpbh = rpb + (h*49 + rbi)*49 + rbj;

  float qv[6];
  #pragma unroll
  for (int d=0; d<6; ++d) qv[d] = q[p*24 + h*6 + d];

  // window walk: position nb = lane + 64*it; (a,cc) = (nb/25, nb%25).
  // per-iteration increment: +64 = +2 rows +14 cols, one carry max.
  // LDS offset r3 = rowofs + (a*26+cc)*3: delta 198 (no carry) / 201 (carry)
  // rpb offset ro = a*49+cc:              delta 112 (no carry) / 136 (carry)
  int aw = lane/25;
  int cw = lane - aw*25;
  float lgv[10];
  float lmax = -1e30f;
  {
    int a = aw, cc = cw;
    int r3 = rowofs + (a*26 + cc)*3;
    int ro = a*49 + cc;
    #pragma unroll
    for (int it=0; it<10; ++it){
      bool ok = (it < 9) || (lane < 49);       // nb < 625
      int r3c = ok ? r3 : rowofs;
      unsigned k0 = kt[r3c], k1 = kt[r3c+1], k2 = kt[r3c+2];
      float lg = qv[0]*blo(k0)+qv[1]*bhi(k0)+qv[2]*blo(k1)
               + qv[3]*bhi(k1)+qv[4]*blo(k2)+qv[5]*bhi(k2);
      lg += rpbh[ok ? ro : 0];
      lg = ok ? lg : -1e30f;
      lgv[it] = lg;
      lmax = fmaxf(lmax, lg);
      cc += 14; bool cy = cc >= 25;
      cc = cy ? cc - 25 : cc;
      r3 += cy ? 201 : 198;
      ro += cy ? 136 : 112;
    }
  }
  lmax = wred_max(lmax);
  float lsum = 0.f;
  #pragma unroll
  for (int it=0; it<10; ++it){
    float pe = __expf(lgv[it]-lmax);
    lgv[it] = pe; lsum += pe;
  }
  lsum = wred_sum(lsum);
  float acc[6] = {0,0,0,0,0,0};
  {
    int cc = cw;
    int r3 = rowofs + (aw*26 + cw)*3 + 8112;   // vt = kt + 8112
    #pragma unroll
    for (int it=0; it<10; ++it){
      bool ok = (it < 9) || (lane < 49);
      int r3c = ok ? r3 : (rowofs + 8112);     // pe = 0 there anyway
      unsigned v0 = kv[r3c], v1 = kv[r3c+1], v2 = kv[r3c+2];
      float pe = lgv[it];
      acc[0] += pe*blo(v0); acc[1] += pe*bhi(v0);
      acc[2] += pe*blo(v1); acc[3] += pe*bhi(v1);
      acc[4] += pe*blo(v2); acc[5] += pe*bhi(v2);
      cc += 14; bool cy = cc >= 25;
      cc = cy ? cc - 25 : cc;
      r3 += cy ? 201 : 198;
    }
  }
  float inv = frcp(lsum);
  #pragma unroll
  for (int d=0; d<6; ++d) acc[d] = wred_sum(acc[d])*inv;

  __syncthreads();               // all kt/vt reads done; kv reusable
  if (lane == 0){
    #pragma unroll
    for (int d=0; d<6; ++d) aop[px*24 + h*6 + d] = acc[d];
  }
  __syncthreads();

  // proj: 4 pixels x 24 channels
  if (tid < 96){
    int pp = tid / 24, c = tid - (tid/24)*24;
    float a2 = pb[c];
    const float* wr = pw + c*24;
    #pragma unroll
    for (int k=0;k<24;++k) a2 += aop[pp*24+k]*wr[k];
    x4[pp*24+c] = a2;
  }
  __syncthreads();

  if (MODE == 0){
    // qkv for next layer: 4 pixels x 72
    if (tid < 288){
      int pp = tid / 72, g = tid - (tid/72)*72;
      float a2 = qkv_b[g];
      const float* wr = qkv_w + g*24;
      #pragma unroll
      for (int k=0;k<24;++k) a2 += x4[pp*24+k]*wr[k];
      int ppi = i0 + (pp>>1), ppj = j0 + (pp&1);
      int pp_ = ppi*88 + ppj;
      int s = g/24, rem = g - s*24;
      if (s==0) q2[pp_*24+rem] = a2*0.4082482904638631f;
      else {
        int hh = rem/6, pos = rem - hh*6;
        bf16* dst = (s==1) ? kh2 : vh2;
        dst[((size_t)hh*NPIX + pp_)*8 + pos] = __float2bfloat16(a2);
      }
    }
  } else {
    // final head: 4 pixels x 5
    if (tid < 20){
      int pp = tid / 5, c = tid - (tid/5)*5;
      float a2 = ob[c];
      const float* wr = ow + c*24;
      #pragma unroll
      for (int k=0;k<24;++k) a2 += x4[pp*24+k]*wr[k];
      int ppi = i0 + (pp>>1), ppj = j0 + (pp&1);
      out[(ppi*88 + ppj)*5 + c] = a2;
    }
  }
}

extern "C" void kernel_launch(void* const* d_in, const int* in_sizes, int n_in,
                              void* d_out, int out_size, void* d_ws, size_t ws_size,
                              hipStream_t stream) {
  const float* feat    = (const float*)d_in[0];
  const int*   cond    = (const int*)  d_in[1];
  const float* mask    = (const float*)d_in[2];
  const float* emb     = (const float*)d_in[3];
  const float* w_ih_l0 = (const float*)d_in[4];
  const float* w_hh_l0 = (const float*)d_in[5];
  const float* b_ih_l0 = (const float*)d_in[6];
  const float* b_hh_l0 = (const float*)d_in[7];
  const float* w_ih_l1 = (const float*)d_in[8];
  const float* w_hh_l1 = (const float*)d_in[9];
  const float* b_ih_l1 = (const float*)d_in[10];
  const float* b_hh_l1 = (const float*)d_in[11];
  const float* qkv_w   = (const float*)d_in[12];
  const float* qkv_b   = (const float*)d_in[13];
  const float* rpb     = (const float*)d_in[14];
  const float* proj_w  = (const float*)d_in[15];
  const float* proj_b  = (const float*)d_in[16];
  const float* out_w   = (const float*)d_in[17];
  const float* out_b   = (const float*)d_in[18];
  float* out = (float*)d_out;

  float* ws  = (float*)d_ws;
  float* Q1  = ws;                    // 135168 floats
  float* Q2  = Q1 + 135168;           // 135168
  bf16*  KH1 = (bf16*)(Q2 + 135168);  // 180224 halves each
  bf16*  VH1 = KH1 + 180224;
  bf16*  KH2 = VH1 + 180224;
  bf16*  VH2 = KH2 + 180224;

  k_core<<<NSEQ, 1024, 0, stream>>>(
      feat, cond, mask, emb,
      w_ih_l0, w_hh_l0, b_ih_l0, b_hh_l0,
      w_ih_l1, w_hh_l1, b_ih_l1, b_hh_l1,
      qkv_w, qkv_b, Q1, KH1, VH1);

  k_natten<0><<<32*44, 1024, 0, stream>>>(
      Q1, KH1, VH1, rpb, proj_w, proj_b, qkv_w, qkv_b,
      nullptr, nullptr, Q2, KH2, VH2, nullptr);

  k_natten<1><<<32*44, 1024, 0, stream>>>(
      Q2, KH2, VH2, rpb, proj_w, proj_b, nullptr, nullptr,
      out_w, out_b, nullptr, nullptr, nullptr, out);
}

// Round 13
// 173.722 us; speedup vs baseline: 1.3956x; 1.0123x over previous
//
#include <hip/hip_runtime.h>
#include <hip/hip_bf16.h>

// B=1 T=64 W=88 HP=48 F0=53 HL=12 GATES=48 NU=24 NH=4 HD=6 K=25
#define NPIX (64*88)          // 5632
#define NSEQ 88
#define TT 64
#define F0 53
#define GATES 48
#define LOG2E 1.4426950408889634f

typedef __hip_bfloat16 bf16;

__device__ __forceinline__ float frcp(float x){ return __builtin_amdgcn_rcpf(x); }
__device__ __forceinline__ float fexp2(float x){ return __builtin_amdgcn_exp2f(x); }
__device__ __forceinline__ float blo(unsigned u){ return __uint_as_float(u<<16); }
__device__ __forceinline__ float bhi(unsigned u){ return __uint_as_float(u & 0xffff0000u); }

// readlane broadcast (constant lane after inlining)
__device__ __forceinline__ float rl(float v, int l){
  return __int_as_float(__builtin_amdgcn_readlane(__float_as_int(v), l));
}
// DPP quad broadcast of lane K within each quad
template<int K> __device__ __forceinline__ float qbcast(float v){
  constexpr int ctrl = K | (K<<2) | (K<<4) | (K<<6);
  return __int_as_float(__builtin_amdgcn_update_dpp(0, __float_as_int(v), ctrl, 0xf, 0xf, true));
}

// ---- wave64 reductions on the VALU pipe (DPP), no LDS-pipe traffic ----
template<int CTRL> __device__ __forceinline__ float dpp_add(float v){
  return v + __int_as_float(__builtin_amdgcn_update_dpp(0, __float_as_int(v), CTRL, 0xf, 0xf, true));
}
template<int CTRL> __device__ __forceinline__ float dpp_max(float v){
  int vi = __float_as_int(v);
  return fmaxf(v, __int_as_float(__builtin_amdgcn_update_dpp(vi, vi, CTRL, 0xf, 0xf, false)));
}
__device__ __forceinline__ float wred_sum(float v){
  v = dpp_add<0x111>(v); v = dpp_add<0x112>(v); v = dpp_add<0x114>(v); v = dpp_add<0x118>(v);
  v = dpp_add<0x142>(v); v = dpp_add<0x143>(v);   // row_bcast:15, row_bcast:31
  return rl(v,63);
}
__device__ __forceinline__ float wred_max(float v){
  v = dpp_max<0x111>(v); v = dpp_max<0x112>(v); v = dpp_max<0x114>(v); v = dpp_max<0x118>(v);
  v = dpp_max<0x142>(v); v = dpp_max<0x143>(v);
  return rl(v,63);
}

// One LSTM direction. Quad-interleaved lane map: lane = 4*u + grp,
// grp 0:i 1:f 2:g 3:o, unit u=lane>>2 (lanes 48-63 duplicate unit 11).
// gbuf entries and whh PRE-SCALED by log2e -> activations use native exp2.
__device__ __forceinline__ void lstm_dir(const float* __restrict__ whh,
    const float* gb_base, float* ybuf, int d, int lane){
  int u = lane >> 2, grp = lane & 3;
  int uc = (u < 12) ? u : 11;
  int j = grp*12 + uc;
  float w[12];
  const float* wb = whh + (d*GATES + j)*12;
  #pragma unroll
  for (int m=0;m<12;++m) w[m] = wb[m]*LOG2E;
  float negs = (grp==2) ? -2.f : -1.f;      // tanh(x)=2*sigm(2x)-1
  float amul = (grp==2) ?  2.f :  1.f;
  float aadd = (grp==2) ? -1.f :  0.f;
  const float* gb = gb_base + (d*TT)*49 + j;
  float hval = 0.f, cval = 0.f;
  int t0 = d ? (TT-1) : 0;
  float gnext = gb[t0*49];
  bool wr = (grp==0) && (u < 12);
  for (int s=0;s<TT;++s){
    int t = d ? (TT-1-s) : s;
    float gg = gnext;
    int tn = d ? max(TT-2-s,0) : min(s+1,TT-1);
    gnext = gb[tn*49];
    float h0=rl(hval,0),  h1=rl(hval,4),  h2=rl(hval,8),   h3=rl(hval,12);
    float h4=rl(hval,16), h5=rl(hval,20), h6=rl(hval,24),  h7=rl(hval,28);
    float h8=rl(hval,32), h9=rl(hval,36), h10=rl(hval,40), h11=rl(hval,44);
    float a0 = gg + h0*w[0] + h4*w[4] + h8*w[8];
    float a1 = h1*w[1] + h5*w[5] + h9*w[9];
    float a2 = h2*w[2] + h6*w[6] + h10*w[10];
    float a3 = h3*w[3] + h7*w[7] + h11*w[11];
    float dot = (a0+a1)+(a2+a3);               // log2e-scaled
    float act = amul*frcp(1.f + fexp2(negs*dot)) + aadd;
    float ai = qbcast<0>(act);
    float af = qbcast<1>(act);
    float ag = qbcast<2>(act);
    float ao = qbcast<3>(act);
    float cn = af*cval + ai*ag;
    float th = 2.f*frcp(1.f + fexp2(-2.885390081777927f*cn)) - 1.f;
    hval = ao*th; cval = cn;
    if (wr) ybuf[t*25 + d*12 + u] = hval;
  }
}

// ============ D1: whole LSTM stack + qkv. 88 blocks x 1024 threads =========
// smem PADDED to 86 KB: forces static occupancy model to 1 block/CU
// (= 4 waves/SIMD), raising the allocator's VGPR budget to 128 so the
// GEMM phases get ILP. Grid is 88 blocks on 256 CUs -> 1 block/CU anyway,
// so the padding costs nothing. (R7/R8/R12 builds chose 32 VGPR targeting
// 8 waves/SIMD that can never materialize; cost ~8-10 us.)
__global__ __launch_bounds__(1024, 4) void k_core(
    const float* __restrict__ feat, const int* __restrict__ cond,
    const float* __restrict__ mask, const float* __restrict__ emb,
    const float* __restrict__ wih0, const float* __restrict__ whh0,
    const float* __restrict__ bih0, const float* __restrict__ bhh0,
    const float* __restrict__ wih1, const float* __restrict__ whh1,
    const float* __restrict__ bih1, const float* __restrict__ bhh1,
    const float* __restrict__ qkv_w, const float* __restrict__ qkv_b,
    float* __restrict__ q, bf16* __restrict__ kh, bf16* __restrict__ vh){
  int n = (blockIdx.x & 7)*11 + (blockIdx.x >> 3);   // XCD-aware remap
  int tid = threadIdx.x;
  int wave = tid >> 6; int lane = tid & 63;
  __shared__ float smem[21504];       // 86016 B declared (padding: see above)
  float* gbuf = smem;                 // 2*64*49 = 6272
  float* sx   = smem + 6272;          // 64*53  = 3392
  float* y0   = smem + 6272+3392;     // 64*25  = 1600
  float* y1   = smem + 6272+4992;     // 64*25  = 1600
  float* outb = smem;                 // 64*73  = 4672 (aliases gbuf, used last)

  for (int idx = tid; idx < TT*F0; idx += 1024){
    int t = idx / F0, f = idx - t*F0;
    float v;
    if (f < 48)      v = feat[(t*48 + f)*88 + n];
    else if (f < 52) v = emb[cond[t*88+n]*4 + (f-48)];
    else             v = mask[t*88+n];
    sx[idx] = v;
  }
  __syncthreads();

  // ---- phase A: layer-0 gate GEMM (lane = t, wave = 6 gate rows) ----
  {
    int wu = __builtin_amdgcn_readfirstlane(wave);
    int dd = wu >> 3, jg = wu & 7;
    const float* w0 = wih0 + (dd*GATES + jg*6)*F0;
    const float* xr = sx + lane*F0;
    float a0[6], a1[6];
    #pragma unroll
    for (int k=0;k<6;++k){
      int j = dd*GATES + jg*6 + k;
      a0[k] = bih0[j] + bhh0[j];
      a1[k] = 0.f;
    }
    #pragma unroll
    for (int f=0; f<52; f+=2){
      float x0 = xr[f], x1 = xr[f+1];
      #pragma unroll
      for (int k=0;k<6;++k){
        a0[k] += x0*w0[k*F0+f];
        a1[k] += x1*w0[k*F0+f+1];
      }
    }
    {
      float x0 = xr[52];
      #pragma unroll
      for (int k=0;k<6;++k) a0[k] += x0*w0[k*F0+52];
    }
    float* go = gbuf + (dd*TT + lane)*49 + jg*6;
    #pragma unroll
    for (int k=0;k<6;++k) go[k] = (a0[k] + a1[k])*LOG2E;
  }
  __syncthreads();

  if (wave < 2) lstm_dir(whh0, gbuf, y0, wave, lane);
  __syncthreads();

  // ---- phase B: layer-1 gate GEMM ----
  {
    int wu = __builtin_amdgcn_readfirstlane(wave);
    int dd = wu >> 3, jg = wu & 7;
    const float* w1p = wih1 + (dd*GATES + jg*6)*24;
    const float* xr = y0 + lane*25;
    float a0[6], a1[6];
    #pragma unroll
    for (int k=0;k<6;++k){
      int j = dd*GATES + jg*6 + k;
      a0[k] = bih1[j] + bhh1[j];
      a1[k] = 0.f;
    }
    #pragma unroll
    for (int c=0; c<24; c+=2){
      float x0 = xr[c], x1 = xr[c+1];
      #pragma unroll
      for (int k=0;k<6;++k){
        a0[k] += x0*w1p[k*24+c];
        a1[k] += x1*w1p[k*24+c+1];
      }
    }
    float* go = gbuf + (dd*TT + lane)*49 + jg*6;
    #pragma unroll
    for (int k=0;k<6;++k) go[k] = (a0[k] + a1[k])*LOG2E;
  }
  __syncthreads();

  if (wave < 2) lstm_dir(whh1, gbuf, y1, wave, lane);
  __syncthreads();

  // ---- qkv GEMM (72 x 24), waves 0-11, lane = t ----
  if (wave < 12){
    int wu = __builtin_amdgcn_readfirstlane(wave);
    int g0 = wu*6;
    const float* qw = qkv_w + g0*24;
    const float* xr = y1 + lane*25;
    float a0[6], a1[6];
    #pragma unroll
    for (int k=0;k<6;++k){ a0[k] = qkv_b[g0+k]; a1[k] = 0.f; }
    #pragma unroll
    for (int c=0; c<24; c+=2){
      float x0 = xr[c], x1 = xr[c+1];
      #pragma unroll
      for (int k=0;k<6;++k){
        a0[k] += x0*qw[k*24+c];
        a1[k] += x1*qw[k*24+c+1];
      }
    }
    float* oo = outb + lane*73 + g0;
    #pragma unroll
    for (int k=0;k<6;++k) oo[k] = a0[k] + a1[k];
  }
  __syncthreads();

  for (int idx = tid; idx < TT*72; idx += 1024){
    int gq = idx % 72; int t = idx / 72;
    int p = t*88 + n;
    float acc = outb[t*73 + gq];
    int s = gq/24, rem = gq - s*24;
    if (s==0) q[p*24+rem] = acc*0.4082482904638631f;   // 1/sqrt(HD)
    else {
      int hh = rem/6, pos = rem - hh*6;
      bf16* dst = (s==1) ? kh : vh;
      dst[((size_t)hh*NPIX + p)*8 + pos] = __float2bfloat16(acc);
    }
  }
}

// ============ D2/D3: merged natten layer (tiled, all heads per block) ======
// Block = 2x2 pixel tile x 4 heads = 16 pixel-head waves (1024 threads).
// K+V staged to LDS once for all heads (stride-3 dwords, conflict-free).
// Division-free incremental window walk (validated bit-identical in R11).
// DPP (VALU-pipe) reductions. MODE 0: epilogue proj+qkv -> q2/kh2/vh2.
// MODE 1: epilogue proj+out head -> out.
template<int MODE>
__global__ __launch_bounds__(1024, 8) void k_natten(
    const float* __restrict__ q, const bf16* __restrict__ kh,
    const bf16* __restrict__ vh, const float* __restrict__ rpb,
    const float* __restrict__ pw, const float* __restrict__ pb,
    const float* __restrict__ qkv_w, const float* __restrict__ qkv_b,
    const float* __restrict__ ow, const float* __restrict__ ob,
    float* __restrict__ q2, bf16* __restrict__ kh2, bf16* __restrict__ vh2,
    float* __restrict__ out){
  int bid = blockIdx.x;
  int b = (bid & 7)*176 + (bid >> 3);          // XCD-aware remap (1408 = 8*176)
  int ti = b / 44, tj = b - ti*44;
  int i0 = ti*2, j0 = tj*2;
  int tid = threadIdx.x;
  int w = tid >> 6; int lane = tid & 63;
  int osi = min(max(i0-12,0),39);
  int osj = min(max(j0-12,0),63);

  // staged region: 26 rows x 26 cols x 4 heads; 3 dwords per row (6 bf16)
  __shared__ unsigned kv[16224];               // 64896 B
  unsigned* kt = kv;                           // [4][676*3]
  unsigned* vt = kv + 8112;
  float* aop = (float*)kv;                     // aliases kt after attention
  float* x4  = aop + 96;

  const uint4* kg = (const uint4*)kh;
  const uint4* vg = (const uint4*)vh;
  for (int idx = tid; idx < 2704; idx += 1024){
    int h = idx / 676; int r = idx - h*676;
    int a = r / 26, cc = r - a*26;
    int gi = min(osi + a, 63), gj = min(osj + cc, 87);
    int src = h*NPIX + gi*88 + gj;
    uint4 kr = kg[src];
    uint4 vr = vg[src];
    int o = idx*3;
    kt[o] = kr.x; kt[o+1] = kr.y; kt[o+2] = kr.z;
    vt[o] = vr.x; vt[o+1] = vr.y; vt[o+2] = vr.z;
  }
  __syncthreads();

  int px = w & 3; int h = w >> 2;
  int pi = i0 + (px>>1), pj = j0 + (px&1);
  int p = pi*88 + pj;
  int dsi = min(max(pi-12,0),39) - osi;
  int dsj = min(max(pj-12,0),63) - osj;
  int rbi = osi + dsi - pi + 24;
  int rbj = osj + dsj - pj + 24;
  int hbase = h*2028;                          // h*676*3
  int rowofs = hbase + (dsi*26 + dsj)*3;
  const float* rpbh = rpb + (h*49 + rbi)*49 + rbj;

  float qv[6];
  #pragma unroll
  for (int d=0; d<6; ++d) qv[d] = q[p*24 + h*6 + d];

  // window walk: position nb = lane + 64*it; (a,cc) = (nb/25, nb%25).
  // per-iteration increment: +64 = +2 rows +14 cols, one carry max.
  // LDS offset r3 = rowofs + (a*26+cc)*3: delta 198 (no carry) / 201 (carry)
  // rpb offset ro = a*49+cc:              delta 112 (no carry) / 136 (carry)
  int aw = lane/25;
  int cw = lane - aw*25;
  float lgv[10];
  float lmax = -1e30f;
  {
    int a = aw, cc = cw;
    int r3 = rowofs + (a*26 + cc)*3;
    int ro = a*49 + cc;
    #pragma unroll
    for (int it=0; it<10; ++it){
      bool ok = (it < 9) || (lane < 49);       // nb < 625
      int r3c = ok ? r3 : rowofs;
      unsigned k0 = kt[r3c], k1 = kt[r3c+1], k2 = kt[r3c+2];
      float lg = qv[0]*blo(k0)+qv[1]*bhi(k0)+qv[2]*blo(k1)
               + qv[3]*bhi(k1)+qv[4]*blo(k2)+qv[5]*bhi(k2);
      lg += rpbh[ok ? ro : 0];
      lg = ok ? lg : -1e30f;
      lgv[it] = lg;
      lmax = fmaxf(lmax, lg);
      cc += 14; bool cy = cc >= 25;
      cc = cy ? cc - 25 : cc;
      r3 += cy ? 201 : 198;
      ro += cy ? 136 : 112;
    }
  }
  lmax = wred_max(lmax);
  float lsum = 0.f;
  #pragma unroll
  for (int it=0; it<10; ++it){
    float pe = __expf(lgv[it]-lmax);
    lgv[it] = pe; lsum += pe;
  }
  lsum = wred_sum(lsum);
  float acc[6] = {0,0,0,0,0,0};
  {
    int cc = cw;
    int r3 = rowofs + (aw*26 + cw)*3 + 8112;   // vt = kt + 8112
    #pragma unroll
    for (int it=0; it<10; ++it){
      bool ok = (it < 9) || (lane < 49);
      int r3c = ok ? r3 : (rowofs + 8112);     // pe = 0 there anyway
      unsigned v0 = kv[r3c], v1 = kv[r3c+1], v2 = kv[r3c+2];
      float pe = lgv[it];
      acc[0] += pe*blo(v0); acc[1] += pe*bhi(v0);
      acc[2] += pe*blo(v1); acc[3] += pe*bhi(v1);
      acc[4] += pe*blo(v2); acc[5] += pe*bhi(v2);
      cc += 14; bool cy = cc >= 25;
      cc = cy ? cc - 25 : cc;
      r3 += cy ? 201 : 198;
    }
  }
  float inv = frcp(lsum);
  #pragma unroll
  for (int d=0; d<6; ++d) acc[d] = wred_sum(acc[d])*inv;

  __syncthreads();               // all kt/vt reads done; kv reusable
  if (lane == 0){
    #pragma unroll
    for (int d=0; d<6; ++d) aop[px*24 + h*6 + d] = acc[d];
  }
  __syncthreads();

  // proj: 4 pixels x 24 channels
  if (tid < 96){
    int pp = tid / 24, c = tid - (tid/24)*24;
    float a2 = pb[c];
    const float* wr = pw + c*24;
    #pragma unroll
    for (int k=0;k<24;++k) a2 += aop[pp*24+k]*wr[k];
    x4[pp*24+c] = a2;
  }
  __syncthreads();

  if (MODE == 0){
    // qkv for next layer: 4 pixels x 72
    if (tid < 288){
      int pp = tid / 72, g = tid - (tid/72)*72;
      float a2 = qkv_b[g];
      const float* wr = qkv_w + g*24;
      #pragma unroll
      for (int k=0;k<24;++k) a2 += x4[pp*24+k]*wr[k];
      int ppi = i0 + (pp>>1), ppj = j0 + (pp&1);
      int pp_ = ppi*88 + ppj;
      int s = g/24, rem = g - s*24;
      if (s==0) q2[pp_*24+rem] = a2*0.4082482904638631f;
      else {
        int hh = rem/6, pos = rem - hh*6;
        bf16* dst = (s==1) ? kh2 : vh2;
        dst[((size_t)hh*NPIX + pp_)*8 + pos] = __float2bfloat16(a2);
      }
    }
  } else {
    // final head: 4 pixels x 5
    if (tid < 20){
      int pp = tid / 5, c = tid - (tid/5)*5;
      float a2 = ob[c];
      const float* wr = ow + c*24;
      #pragma unroll
      for (int k=0;k<24;++k) a2 += x4[pp*24+k]*wr[k];
      int ppi = i0 + (pp>>1), ppj = j0 + (pp&1);
      out[(ppi*88 + ppj)*5 + c] = a2;
    }
  }
}

extern "C" void kernel_launch(void* const* d_in, const int* in_sizes, int n_in,
                              void* d_out, int out_size, void* d_ws, size_t ws_size,
                              hipStream_t stream) {
  const float* feat    = (const float*)d_in[0];
  const int*   cond    = (const int*)  d_in[1];
  const float* mask    = (const float*)d_in[2];
  const float* emb     = (const float*)d_in[3];
  const float* w_ih_l0 = (const float*)d_in[4];
  const float* w_hh_l0 = (const float*)d_in[5];
  const float* b_ih_l0 = (const float*)d_in[6];
  const float* b_hh_l0 = (const float*)d_in[7];
  const float* w_ih_l1 = (const float*)d_in[8];
  const float* w_hh_l1 = (const float*)d_in[9];
  const float* b_ih_l1 = (const float*)d_in[10];
  const float* b_hh_l1 = (const float*)d_in[11];
  const float* qkv_w   = (const float*)d_in[12];
  const float* qkv_b   = (const float*)d_in[13];
  const float* rpb     = (const float*)d_in[14];
  const float* proj_w  = (const float*)d_in[15];
  const float* proj_b  = (const float*)d_in[16];
  const float* out_w   = (const float*)d_in[17];
  const float* out_b   = (const float*)d_in[18];
  float* out = (float*)d_out;

  float* ws  = (float*)d_ws;
  float* Q1  = ws;                    // 135168 floats
  float* Q2  = Q1 + 135168;           // 135168
  bf16*  KH1 = (bf16*)(Q2 + 135168);  // 180224 halves each
  bf16*  VH1 = KH1 + 180224;
  bf16*  KH2 = VH1 + 180224;
  bf16*  VH2 = KH2 + 180224;

  k_core<<<NSEQ, 1024, 0, stream>>>(
      feat, cond, mask, emb,
      w_ih_l0, w_hh_l0, b_ih_l0, b_hh_l0,
      w_ih_l1, w_hh_l1, b_ih_l1, b_hh_l1,
      qkv_w, qkv_b, Q1, KH1, VH1);

  k_natten<0><<<32*44, 1024, 0, stream>>>(
      Q1, KH1, VH1, rpb, proj_w, proj_b, qkv_w, qkv_b,
      nullptr, nullptr, Q2, KH2, VH2, nullptr);

  k_natten<1><<<32*44, 1024, 0, stream>>>(
      Q2, KH2, VH2, rpb, proj_w, proj_b, nullptr, nullptr,
      out_w, out_b, nullptr, nullptr, nullptr, out);
}